// Round 15
// baseline (2718.890 us; speedup 1.0000x reference)
//
#include <hip/hip_runtime.h>
#include <math.h>

#define H_IN   48
#define W_IN   48
#define INC    32
#define OUTC   3
#define FT     16
#define Dn     1536
#define D8n    192
#define D4n    384
#define D2n    768

typedef _Float16 h16;
typedef _Float16 f16x8 __attribute__((ext_vector_type(8)));
typedef _Float16 f16x4 __attribute__((ext_vector_type(4)));
typedef float    f32x4 __attribute__((ext_vector_type(4)));

#define MFMA16(a, b, c) __builtin_amdgcn_mfma_f32_16x16x32_f16((a), (b), (c), 0, 0, 0)

__device__ __forceinline__ int reflect48(int i) {
    return (i < 0) ? -i : ((i > 47) ? 94 - i : i);
}

__device__ __forceinline__ float tanhf_fast(float x) {
    float e = __expf(2.f * x);
    return 1.f - 2.f / (e + 1.f);
}

// row-XOR swizzle: byte column ^ ((row&7)<<4)
#define SWZ(p, bc) ((bc) ^ (((p) & 7) << 4))

// ---------------- feature_trans conv ----------------
__global__ __launch_bounds__(256) void ft_kernel(const float* __restrict__ lr,
                                                 const float* __restrict__ ft_w,
                                                 const float* __restrict__ ft_b,
                                                 float* __restrict__ ftmap) {
    int idx = blockIdx.x * 256 + threadIdx.x;
    if (idx >= 2 * FT * H_IN * W_IN) return;
    int x = idx % W_IN;
    int y = (idx / W_IN) % H_IN;
    int o = (idx / (W_IN * H_IN)) % FT;
    int bb = idx / (W_IN * H_IN * FT);
    float acc = ft_b[o];
    for (int c = 0; c < INC; ++c) {
        const float* lrc = lr + ((bb * INC + c) * H_IN) * W_IN;
        const float* wc  = ft_w + ((o * INC + c) * 4) * 4;
        #pragma unroll
        for (int dy = 0; dy < 4; ++dy) {
            int ry = reflect48(y + dy - 1);
            #pragma unroll
            for (int dx = 0; dx < 4; ++dx) {
                int rx = reflect48(x + dx - 1);
                acc += lrc[ry * W_IN + rx] * wc[dy * 4 + dx];
            }
        }
    }
    ftmap[idx] = acc;
}

// ---------------- weight transpose + f32->f16 ----------------
// bids 0..1511: big-weight transposes. bids 1512/1513: l{1,2}w1 -> [192][24] f16
__global__ __launch_bounds__(256) void prep_kernel(const float* __restrict__ l1w2,
                                                   const float* __restrict__ l2w2,
                                                   const float* __restrict__ l3w1,
                                                   const float* __restrict__ l3w2,
                                                   const float* __restrict__ l1w1,
                                                   const float* __restrict__ l2w1,
                                                   h16* __restrict__ w12t, h16* __restrict__ w22t,
                                                   h16* __restrict__ w31t, h16* __restrict__ w32t,
                                                   h16* __restrict__ w11t, h16* __restrict__ w21t) {
    __shared__ float tile[32][33];
    int bid = blockIdx.x;
    if (bid >= 1512) {
        const float* s = (bid == 1512) ? l1w1 : l2w1;
        h16* d = (bid == 1512) ? w11t : w21t;
        int j = threadIdx.x;
        if (j < 192) {
            #pragma unroll
            for (int i = 0; i < 20; ++i) d[j * 24 + i] = (h16)s[i * 192 + j];
            #pragma unroll
            for (int i = 20; i < 24; ++i) d[j * 24 + i] = (h16)0.f;
        }
        return;
    }
    const float* src; h16* dst; int K, N, t0;
    if (bid < 36)      { src = l1w2; dst = w12t; K = 192; N = 192;  t0 = 0; }
    else if (bid < 72) { src = l2w2; dst = w22t; K = 192; N = 192;  t0 = 36; }
    else if (bid < 360){ src = l3w1; dst = w31t; K = 384; N = 768;  t0 = 72; }
    else               { src = l3w2; dst = w32t; K = 768; N = 1536; t0 = 360; }
    int t = bid - t0;
    int ntx = N >> 5;
    int kt = t / ntx, nt = t - kt * ntx;
    int k0 = kt << 5, n0 = nt << 5;
    int tx = threadIdx.x & 31, ty = threadIdx.x >> 5;
    #pragma unroll
    for (int i = 0; i < 4; ++i)
        tile[ty + i * 8][tx] = src[(k0 + ty + i * 8) * N + n0 + tx];
    __syncthreads();
    #pragma unroll
    for (int i = 0; i < 4; ++i)
        dst[(n0 + ty + i * 8) * K + k0 + tx] = (h16)tile[tx][ty + i * 8];
}

// =================================================================
// Kernel A: phases 0-4 (MLP up to g), 32 pixels/block, writes g-frags
// =================================================================
#define A_OFF_H1   0
#define A_OFF_H2   12288
#define A_OFF_OSF  24576
#define A_OFF_F    0
#define A_OFF_G    0
#define A_S_BYTES  49152

__global__ __launch_bounds__(256, 3) void fused_a(
    const float* __restrict__ ftmap,
    const h16* __restrict__ W11T, const float* __restrict__ l1b1,
    const h16* __restrict__ W21T, const float* __restrict__ l2b1,
    const float* __restrict__ l1b2, const float* __restrict__ l2b2,
    const float* __restrict__ l3b1,
    const h16* __restrict__ W12T, const h16* __restrict__ W22T,
    const h16* __restrict__ W31T,
    h16* __restrict__ Gf)
{
    __shared__ __align__(16) char S[A_S_BYTES];

    const int tid  = threadIdx.x;
    const int lane = tid & 63;
    const int wv   = tid >> 6;
    const int bid  = blockIdx.x;
    const int b    = bid / 1152;
    const int rem  = bid % 1152;
    const int h    = rem / 6;
    const int w0   = (rem % 6) * 32;

    const float ch = (h + 1) * 0.25f - 0.625f;
    const int   fh = (int)floorf(ch);
    const float offh = (float)fh - ch;
    const int   rfh = reflect48(fh);

    float* s_osf = (float*)(S + A_OFF_OSF);

    // ---------- phase 0: osf ----------
    if (tid < 32) {
        int w = w0 + tid;
        float cw = (w + 1) * 0.25f - 0.625f;
        int fw = (int)floorf(cw);
        float* o = s_osf + tid * 20;
        o[16] = offh; o[17] = (float)fw - cw; o[18] = 4.f; o[19] = 4.f;
    }
    {   // srf gather: 32p x 16ch
        int p = tid >> 3;
        int c0 = (tid & 7) * 2;
        int w = w0 + p;
        float cw = (w + 1) * 0.25f - 0.625f;
        int rfw = reflect48((int)floorf(cw));
        float* o = s_osf + p * 20;
        o[c0]     = ftmap[((b * FT + c0) * H_IN + rfh) * W_IN + rfw];
        o[c0 + 1] = ftmap[((b * FT + c0 + 1) * H_IN + rfh) * W_IN + rfw];
    }
    __syncthreads();

    // ---------- phase 1: h{1,2} = tanh(osf @ W1 + b), W1 rows f16 contiguous ----------
    for (int idx = tid; idx < 2 * 32 * D8n; idx += 256) {
        int br = idx / 6144;
        int r2 = idx - br * 6144;
        int p  = r2 / D8n;
        int j  = r2 - p * D8n;
        const h16* Wt = (br ? W21T : W11T) + j * 24;
        const float* B = br ? l2b1 : l1b1;
        const float* o = s_osf + p * 20;
        float acc = B[j];
        f16x8 wa = *(const f16x8*)(Wt);
        f16x8 wb = *(const f16x8*)(Wt + 8);
        f16x4 wc = *(const f16x4*)(Wt + 16);
        #pragma unroll
        for (int i = 0; i < 8; ++i) acc += o[i] * (float)wa[i];
        #pragma unroll
        for (int i = 0; i < 8; ++i) acc += o[8 + i] * (float)wb[i];
        #pragma unroll
        for (int i = 0; i < 4; ++i) acc += o[16 + i] * (float)wc[i];
        int base = br ? A_OFF_H2 : A_OFF_H1;
        *(h16*)(S + base + p * 384 + SWZ(p, j * 2)) = (h16)tanhf_fast(acc);
    }
    __syncthreads();

    // ---------- phase 2 A-load ----------
    f16x8 Ah[2][2][6];
    {
        int pr = lane & 15, kg = (lane >> 4) << 3;
        #pragma unroll
        for (int br = 0; br < 2; ++br)
            #pragma unroll
            for (int rt = 0; rt < 2; ++rt) {
                int p = rt * 16 + pr;
                #pragma unroll
                for (int kf = 0; kf < 6; ++kf) {
                    int k0 = kf * 32 + kg;
                    Ah[br][rt][kf] = *(const f16x8*)(S + (br ? A_OFF_H2 : A_OFF_H1) + p * 384 + SWZ(p, k0 * 2));
                }
            }
    }
    __syncthreads();

    // ---------- phase 2 compute + merge -> f ----------
    {
        int pr = lane & 15, kg = (lane >> 4) << 3;
        #pragma unroll
        for (int cc = 0; cc < 3; ++cc) {
            int c = wv * 3 + cc;
            int n = c * 16 + pr;
            f32x4 a00 = {0.f,0.f,0.f,0.f}, a01 = a00, a10 = a00, a11 = a00;
            #pragma unroll
            for (int kf = 0; kf < 6; ++kf) {
                int koff = kf * 32 + kg;
                f16x8 b0 = *(const f16x8*)(W12T + n * D8n + koff);
                f16x8 b1 = *(const f16x8*)(W22T + n * D8n + koff);
                a00 = MFMA16(Ah[0][0][kf], b0, a00);
                a01 = MFMA16(Ah[0][1][kf], b0, a01);
                a10 = MFMA16(Ah[1][0][kf], b1, a10);
                a11 = MFMA16(Ah[1][1][kf], b1, a11);
            }
            float bf1 = l1b2[n], bf2 = l2b2[n];
            #pragma unroll
            for (int rt = 0; rt < 2; ++rt) {
                #pragma unroll
                for (int r = 0; r < 4; ++r) {
                    int p = rt * 16 + ((lane >> 4) << 2) + r;
                    float f1 = (rt ? a01[r] : a00[r]) + bf1;
                    float f2 = (rt ? a11[r] : a10[r]) + bf2;
                    *(h16*)(S + A_OFF_F + p * 768 + SWZ(p, n * 2))         = (h16)tanhf_fast(f1 * f2);
                    *(h16*)(S + A_OFF_F + p * 768 + SWZ(p, (n + D8n) * 2)) = (h16)tanhf_fast(f1);
                }
            }
        }
    }
    __syncthreads();

    // ---------- phase 4 A-load ----------
    f16x8 Af[2][12];
    {
        int pr = lane & 15, kg = (lane >> 4) << 3;
        #pragma unroll
        for (int rt = 0; rt < 2; ++rt) {
            int p = rt * 16 + pr;
            #pragma unroll
            for (int kf = 0; kf < 12; ++kf) {
                int k0 = kf * 32 + kg;
                Af[rt][kf] = *(const f16x8*)(S + A_OFF_F + p * 768 + SWZ(p, k0 * 2));
            }
        }
    }
    __syncthreads();

    // ---------- phase 4 compute: g = leaky(f @ l3w1 + b) -> g LDS ----------
    {
        int pr = lane & 15, kg = (lane >> 4) << 3;
        #pragma unroll
        for (int q = 0; q < 3; ++q) {
            int ntb = wv * 12 + q * 4;
            f32x4 acc[4][2];
            #pragma unroll
            for (int nn = 0; nn < 4; ++nn) { acc[nn][0] = (f32x4){0.f,0.f,0.f,0.f}; acc[nn][1] = acc[nn][0]; }
            for (int kf = 0; kf < 12; ++kf) {
                int koff = kf * 32 + kg;
                f16x8 bq[4];
                #pragma unroll
                for (int nn = 0; nn < 4; ++nn)
                    bq[nn] = *(const f16x8*)(W31T + ((ntb + nn) * 16 + pr) * D4n + koff);
                #pragma unroll
                for (int nn = 0; nn < 4; ++nn) {
                    acc[nn][0] = MFMA16(Af[0][kf], bq[nn], acc[nn][0]);
                    acc[nn][1] = MFMA16(Af[1][kf], bq[nn], acc[nn][1]);
                }
            }
            #pragma unroll
            for (int nn = 0; nn < 4; ++nn) {
                int n = (ntb + nn) * 16 + pr;
                float bb = l3b1[n];
                #pragma unroll
                for (int rt = 0; rt < 2; ++rt) {
                    #pragma unroll
                    for (int r = 0; r < 4; ++r) {
                        int p = rt * 16 + ((lane >> 4) << 2) + r;
                        float gv = acc[nn][rt][r] + bb;
                        gv = (gv > 0.f) ? gv : 0.01f * gv;
                        *(h16*)(S + A_OFF_G + p * 1536 + SWZ(p, n * 2)) = (h16)gv;
                    }
                }
            }
        }
    }
    __syncthreads();

    // ---------- phase 5': export g as MFMA B-fragments, non-temporal ----------
    {
        int pr = lane & 15, kg = lane >> 4;
        int ptg0 = (b * 192 + h) * 12 + (w0 >> 4);
        #pragma unroll
        for (int i = 0; i < 12; ++i) {
            int pair = wv * 12 + i;           // 0..47
            int rt = pair / 24, kf = pair % 24;
            int p = rt * 16 + pr;
            f16x8 v = *(const f16x8*)(S + A_OFF_G + p * 1536 + SWZ(p, (kf * 32 + kg * 8) * 2));
            size_t e = ((size_t)((ptg0 + rt) * 24 + kf) * 4 + kg) * 16 + pr;
            __builtin_nontemporal_store(v, (f16x8*)(Gf + e * 8));
        }
    }
}

// =================================================================
// Kernel B v11: r12-exact structure (K-split, rotating W triples,
// compiler scheduling) with PACKED float4 sel cache:
// s_q[c][k1][j] = {v[j],v[j+1],v[j+2],v[j+3]} -> epilogue does ONE
// aligned ds_read_b128 per pixel-tile instead of 4 scalar b32 reads
// (16 -> 4 LDS instrs per step).
// =================================================================
__global__ __launch_bounds__(512, 4) void gemm_b(
    const float* __restrict__ lr,
    const h16* __restrict__ Gf,
    const h16* __restrict__ W32T,
    const float* __restrict__ l3b2,
    float* __restrict__ out)
{
    __shared__ f32x4 s_q[32][4][20];          // 40960 B
    __shared__ float s_red[8][64][3];         // 6144 B

    const int tid  = threadIdx.x;
    const int lane = tid & 63;
    const int wvv  = tid >> 6;                // 0..7
    const int pr   = lane & 15;
    const int kg   = lane >> 4;               // 0..3

    const int bid = blockIdx.x;
    const int b   = bid / 576;
    const int rem = bid % 576;
    const int h   = rem / 3;
    const int w0  = (rem % 3) * 64;
    const int w4  = w0 >> 2;

    const float chh = (h + 1) * 0.25f - 0.625f;
    const int fh = (int)floorf(chh);

    // ---------- stage packed reflect-padded lr row cache ----------
    // s_q[c][k1][j][r] = lr[b][c][reflect(fh-1+k1)][reflect(w4-2+j+r)], r=0..3
    for (int idx = tid; idx < 32 * 4 * 20; idx += 512) {
        int c  = idx / 80;
        int r2 = idx - c * 80;
        int k1 = r2 / 20;
        int j  = r2 - k1 * 20;
        int row = reflect48(fh - 1 + k1);
        const float* lrow = lr + ((b * INC + c) * H_IN + row) * W_IN;
        f32x4 v;
        v[0] = lrow[reflect48(w4 - 2 + j)];
        v[1] = lrow[reflect48(w4 - 1 + j)];
        v[2] = lrow[reflect48(w4 + j)];
        v[3] = lrow[reflect48(w4 + 1 + j)];
        s_q[c][k1][j] = v;
    }
    __syncthreads();

    // ---------- bias-dot: s_red[part][p][oc] = sum_{k in part-slice} b[oc*512+k]*sel[p,k]
    {
        int p = tid >> 3, part = tid & 7;
        int jbp = (int)floorf((w0 + p + 1) * 0.25f - 0.625f) - w4 + 1;
        float s0 = 0.f, s1 = 0.f, s2 = 0.f;
        #pragma unroll
        for (int j = 0; j < 16; ++j) {
            int k  = part * 4 + j * 32;
            int c  = k >> 4;
            int k1 = (k >> 2) & 3;
            f32x4 q = s_q[c][k1][jbp];
            float4 ba  = *(const float4*)(l3b2 + k);
            float4 bbv = *(const float4*)(l3b2 + 512 + k);
            float4 bc  = *(const float4*)(l3b2 + 1024 + k);
            #pragma unroll
            for (int r = 0; r < 4; ++r) {
                float sv = q[r];
                s0 += ((const float*)&ba)[r]  * sv;
                s1 += ((const float*)&bbv)[r] * sv;
                s2 += ((const float*)&bc)[r]  * sv;
            }
        }
        s_red[part][p][0] = s0; s_red[part][p][1] = s1; s_red[part][p][2] = s2;
    }
    __syncthreads();

    const int ptB = (b * 192 + h) * 12 + (w0 >> 4);

    // per-lane column offsets into s_q rows, one per pixel-tile
    const int jb0 = (int)floorf((w0 + pr      + 1) * 0.25f - 0.625f) - w4 + 1;
    const int jb1 = (int)floorf((w0 + pr + 16 + 1) * 0.25f - 0.625f) - w4 + 1;
    const int jb2 = (int)floorf((w0 + pr + 32 + 1) * 0.25f - 0.625f) - w4 + 1;
    const int jb3 = (int)floorf((w0 + pr + 48 + 1) * 0.25f - 0.625f) - w4 + 1;

    // ---------- gB frags for this wave's K-slice (kf = wvv*3 + {0,1,2}), nt loads ----------
    f16x8 gB[4][3];
    {
        const h16* Gbase = Gf + (size_t)(kg * 16 + pr) * 8;
        #pragma unroll
        for (int pt = 0; pt < 4; ++pt)
            #pragma unroll
            for (int kfl = 0; kfl < 3; ++kfl)
                gB[pt][kfl] = __builtin_nontemporal_load((const f16x8*)(Gbase +
                    ((size_t)((ptB + pt) * 24 + (wvv * 3 + kfl)) * 64) * 8));
    }

    const h16* Wbase = W32T + (size_t)pr * D2n + wvv * 96 + kg * 8;

    float acc0[4], acc1[4], acc2[4];
    #pragma unroll
    for (int pt = 0; pt < 4; ++pt) { acc0[pt] = 0.f; acc1[pt] = 0.f; acc2[pt] = 0.f; }

    const f32x4 z4 = {0.f, 0.f, 0.f, 0.f};

    f16x8 A0, A1, A2, B0, B1, B2, C0, C1, C2;

    #define LOADW(NT, T0_, T1_, T2_) {                                             \
        int n_ = (NT); n_ = (n_ > 95) ? 95 : n_;                                   \
        const h16* p_ = Wbase + (size_t)n_ * (16 * D2n);                           \
        T0_ = *(const f16x8*)(p_);                                                 \
        T1_ = *(const f16x8*)(p_ + 32);                                            \
        T2_ = *(const f16x8*)(p_ + 64);                                            \
    }

    // step NT: issue load for NT+2 into (N*), 12 MFMA on (W*), packed-sel epilogue
    #define STEP(NT, W0_, W1_, W2_, N0_, N1_, N2_) {                               \
        LOADW((NT) + 2, N0_, N1_, N2_)                                             \
        f32x4 w0_ = MFMA16(W0_, gB[0][0], z4);                                     \
        f32x4 w1_ = MFMA16(W0_, gB[1][0], z4);                                     \
        f32x4 w2_ = MFMA16(W0_, gB[2][0], z4);                                     \
        f32x4 w3_ = MFMA16(W0_, gB[3][0], z4);                                     \
        w0_ = MFMA16(W1_, gB[0][1], w0_);                                          \
        w1_ = MFMA16(W1_, gB[1][1], w1_);                                          \
        w2_ = MFMA16(W1_, gB[2][1], w2_);                                          \
        w3_ = MFMA16(W1_, gB[3][1], w3_);                                          \
        w0_ = MFMA16(W2_, gB[0][2], w0_);                                          \
        w1_ = MFMA16(W2_, gB[1][2], w1_);                                          \
        w2_ = MFMA16(W2_, gB[2][2], w2_);                                          \
        w3_ = MFMA16(W2_, gB[3][2], w3_);                                          \
        const int nt_ = (NT);                                                      \
        const int c_ = nt_ & 31;                                                   \
        f32x4 q0_ = s_q[c_][kg][jb0];                                              \
        f32x4 q1_ = s_q[c_][kg][jb1];                                              \
        f32x4 q2_ = s_q[c_][kg][jb2];                                              \
        f32x4 q3_ = s_q[c_][kg][jb3];                                              \
        float e0_ = w0_[0] * q0_[0] + w0_[1] * q0_[1]                              \
                  + w0_[2] * q0_[2] + w0_[3] * q0_[3];                             \
        float e1_ = w1_[0] * q1_[0] + w1_[1] * q1_[1]                              \
                  + w1_[2] * q1_[2] + w1_[3] * q1_[3];                             \
        float e2_ = w2_[0] * q2_[0] + w2_[1] * q2_[1]                              \
                  + w2_[2] * q2_[2] + w2_[3] * q2_[3];                             \
        float e3_ = w3_[0] * q3_[0] + w3_[1] * q3_[1]                              \
                  + w3_[2] * q3_[2] + w3_[3] * q3_[3];                             \
        const int oc_ = nt_ >> 5;                                                  \
        if (oc_ == 0)      { acc0[0] += e0_; acc0[1] += e1_; acc0[2] += e2_; acc0[3] += e3_; } \
        else if (oc_ == 1) { acc1[0] += e0_; acc1[1] += e1_; acc1[2] += e2_; acc1[3] += e3_; } \
        else               { acc2[0] += e0_; acc2[1] += e1_; acc2[2] += e2_; acc2[3] += e3_; } \
    }

    LOADW(0, A0, A1, A2)
    LOADW(1, B0, B1, B2)
    for (int g = 0; g < 32; ++g) {
        const int t0 = 3 * g;
        STEP(t0,     A0, A1, A2, C0, C1, C2)
        STEP(t0 + 1, B0, B1, B2, A0, A1, A2)
        STEP(t0 + 2, C0, C1, C2, B0, B1, B2)
    }
    #undef LOADW
    #undef STEP

    // ---------- cross-lane (kg) reduce, then += into this wave's s_red slot ----------
    #pragma unroll
    for (int pt = 0; pt < 4; ++pt) {
        float v0 = acc0[pt], v1 = acc1[pt], v2 = acc2[pt];
        v0 += __shfl_xor(v0, 16); v0 += __shfl_xor(v0, 32);
        v1 += __shfl_xor(v1, 16); v1 += __shfl_xor(v1, 32);
        v2 += __shfl_xor(v2, 16); v2 += __shfl_xor(v2, 32);
        if (lane < 16) {
            float* r = &s_red[wvv][pt * 16 + pr][0];
            r[0] += v0; r[1] += v1; r[2] += v2;
        }
    }
    __syncthreads();
    if (tid < 192) {
        int p = tid / 3, oc = tid % 3;
        float s = 0.f;
        #pragma unroll
        for (int wv2 = 0; wv2 < 8; ++wv2) s += s_red[wv2][p][oc];
        out[((b * OUTC + oc) * 192 + h) * 192 + (w0 + p)] = tanhf_fast(s);
    }
}

// =================================================================
// Fallback (round-2 single fused kernel) if ws too small
// =================================================================
__global__ __launch_bounds__(256, 2) void fused_fallback(
    const float* __restrict__ lr, const float* __restrict__ ftmap,
    const float* __restrict__ l1w1, const float* __restrict__ l1b1,
    const float* __restrict__ l2w1, const float* __restrict__ l2b1,
    const float* __restrict__ l1b2, const float* __restrict__ l2b2,
    const float* __restrict__ l3b1, const float* __restrict__ l3b2,
    const h16* __restrict__ W12T, const h16* __restrict__ W22T,
    const h16* __restrict__ W31T, const h16* __restrict__ W32T,
    float* __restrict__ out)
{
    __shared__ __align__(16) char S[63104];
    const int tid  = threadIdx.x;
    const int lane = tid & 63;
    const int wv   = tid >> 6;
    const int bid  = blockIdx.x;
    const int b    = bid / 1152;
    const int rem  = bid % 1152;
    const int h    = rem / 6;
    const int w0   = (rem % 6) * 32;

    const float ch = (h + 1) * 0.25f - 0.625f;
    const int   fh = (int)floorf(ch);
    const float offh = (float)fh - ch;
    const int   rfh = reflect48(fh);

    float* s_osf = (float*)(S + 24576);
    unsigned char* s_sc = (unsigned char*)(S + 61440);
    h16*   s_lrr = (h16*)(S + 49152);
    float* s_red = (float*)(S + 61568);

    if (tid < 128) {
        int p = tid >> 2, k2 = tid & 3;
        int w = w0 + p;
        float cw = (w + 1) * 0.25f - 0.625f;
        int fw = (int)floorf(cw);
        s_sc[p * 4 + k2] = (unsigned char)reflect48(fw - 1 + k2);
        if (k2 == 0) {
            float* o = s_osf + p * 20;
            o[16] = offh; o[17] = (float)fw - cw; o[18] = 4.f; o[19] = 4.f;
        }
    }
    {
        int p = tid >> 3;
        int c0 = (tid & 7) * 2;
        int w = w0 + p;
        float cw = (w + 1) * 0.25f - 0.625f;
        int rfw = reflect48((int)floorf(cw));
        float* o = s_osf + p * 20;
        o[c0]     = ftmap[((b * FT + c0) * H_IN + rfh) * W_IN + rfw];
        o[c0 + 1] = ftmap[((b * FT + c0 + 1) * H_IN + rfh) * W_IN + rfw];
    }
    for (int idx = tid; idx < 32 * 4 * 48; idx += 256) {
        int c = idx / 192, r2 = idx - c * 192, k1 = r2 / 48, col = r2 - k1 * 48;
        int row = reflect48(fh - 1 + k1);
        s_lrr[idx] = (h16)lr[((b * INC + c) * H_IN + row) * W_IN + col];
    }
    for (int idx = tid; idx < 4 * 32 * 3; idx += 256) s_red[idx] = 0.f;
    __syncthreads();

    for (int idx = tid; idx < 2 * 32 * D8n; idx += 256) {
        int br = idx / 6144;
        int r2 = idx - br * 6144;
        int p  = r2 / D8n;
        int j  = r2 - p * D8n;
        const float* W = br ? l2w1 : l1w1;
        const float* B = br ? l2b1 : l1b1;
        const float* o = s_osf + p * 20;
        float acc = B[j];
        #pragma unroll
        for (int i = 0; i < 20; ++i) acc += o[i] * W[i * D8n + j];
        int base = br ? 12288 : 0;
        *(h16*)(S + base + p * 384 + SWZ(p, j * 2)) = (h16)tanhf_fast(acc);
    }
    __syncthreads();

    f16x8 Ah[2][2][6];
    {
        int pr = lane & 15, kg = (lane >> 4) << 3;
        #pragma unroll
        for (int br = 0; br < 2; ++br)
            #pragma unroll
            for (int rt = 0; rt < 2; ++rt) {
                int p = rt * 16 + pr;
                #pragma unroll
                for (int kf = 0; kf < 6; ++kf)
                    Ah[br][rt][kf] = *(const f16x8*)(S + (br ? 12288 : 0) + p * 384 + SWZ(p, (kf * 32 + kg) * 2));
            }
    }
    __syncthreads();

    {
        int pr = lane & 15, kg = (lane >> 4) << 3;
        #pragma unroll
        for (int cc = 0; cc < 3; ++cc) {
            int c = wv * 3 + cc;
            int n = c * 16 + pr;
            f32x4 a00 = {0.f,0.f,0.f,0.f}, a01 = a00, a10 = a00, a11 = a00;
            #pragma unroll
            for (int kf = 0; kf < 6; ++kf) {
                int koff = kf * 32 + kg;
                f16x8 b0 = *(const f16x8*)(W12T + n * D8n + koff);
                f16x8 b1 = *(const f16x8*)(W22T + n * D8n + koff);
                a00 = MFMA16(Ah[0][0][kf], b0, a00);
                a01 = MFMA16(Ah[0][1][kf], b0, a01);
                a10 = MFMA16(Ah[1][0][kf], b1, a10);
                a11 = MFMA16(Ah[1][1][kf], b1, a11);
            }
            float bf1 = l1b2[n], bf2 = l2b2[n];
            #pragma unroll
            for (int rt = 0; rt < 2; ++rt)
                #pragma unroll
                for (int r = 0; r < 4; ++r) {
                    int p = rt * 16 + ((lane >> 4) << 2) + r;
                    float f1 = (rt ? a01[r] : a00[r]) + bf1;
                    float f2 = (rt ? a11[r] : a10[r]) + bf2;
                    *(h16*)(S + p * 768 + SWZ(p, n * 2))         = (h16)tanhf_fast(f1 * f2);
                    *(h16*)(S + p * 768 + SWZ(p, (n + D8n) * 2)) = (h16)tanhf_fast(f1);
                }
        }
    }
    __syncthreads();

    f16x8 Af[2][12];
    {
        int pr = lane & 15, kg = (lane >> 4) << 3;
        #pragma unroll
        for (int rt = 0; rt < 2; ++rt) {
            int p = rt * 16 + pr;
            #pragma unroll
            for (int kf = 0; kf < 12; ++kf)
                Af[rt][kf] = *(const f16x8*)(S + p * 768 + SWZ(p, (kf * 32 + kg) * 2));
        }
    }
    __syncthreads();

    {
        int pr = lane & 15, kg = (lane >> 4) << 3;
        #pragma unroll
        for (int q = 0; q < 3; ++q) {
            int ntb = wv * 12 + q * 4;
            f32x4 acc[4][2];
            #pragma unroll
            for (int nn = 0; nn < 4; ++nn) { acc[nn][0] = (f32x4){0.f,0.f,0.f,0.f}; acc[nn][1] = acc[nn][0]; }
            for (int kf = 0; kf < 12; ++kf) {
                int koff = kf * 32 + kg;
                f16x8 bq[4];
                #pragma unroll
                for (int nn = 0; nn < 4; ++nn)
                    bq[nn] = *(const f16x8*)(W31T + ((ntb + nn) * 16 + pr) * D4n + koff);
                #pragma unroll
                for (int nn = 0; nn < 4; ++nn) {
                    acc[nn][0] = MFMA16(Af[0][kf], bq[nn], acc[nn][0]);
                    acc[nn][1] = MFMA16(Af[1][kf], bq[nn], acc[nn][1]);
                }
            }
            #pragma unroll
            for (int nn = 0; nn < 4; ++nn) {
                int n = (ntb + nn) * 16 + pr;
                float bb = l3b1[n];
                #pragma unroll
                for (int rt = 0; rt < 2; ++rt)
                    #pragma unroll
                    for (int r = 0; r < 4; ++r) {
                        int p = rt * 16 + ((lane >> 4) << 2) + r;
                        float gv = acc[nn][rt][r] + bb;
                        gv = (gv > 0.f) ? gv : 0.01f * gv;
                        *(h16*)(S + p * 1536 + SWZ(p, n * 2)) = (h16)gv;
                    }
            }
        }
    }
    __syncthreads();

    {
        int pr = lane & 15, kg = (lane >> 4) << 3;
        float acc8[2][4];
        #pragma unroll
        for (int rt = 0; rt < 2; ++rt)
            #pragma unroll
            for (int r = 0; r < 4; ++r) acc8[rt][r] = 0.f;
        int cur_oc = (wv * 24) >> 5;

        for (int q = 0; q < 6; ++q) {
            int ntb = wv * 24 + q * 4;
            int oc = ntb >> 5;
            if (oc != cur_oc) {
                #pragma unroll
                for (int rt = 0; rt < 2; ++rt)
                    #pragma unroll
                    for (int r = 0; r < 4; ++r) {
                        float v = acc8[rt][r];
                        v += __shfl_xor(v, 1); v += __shfl_xor(v, 2);
                        v += __shfl_xor(v, 4); v += __shfl_xor(v, 8);
                        if ((lane & 15) == 0) {
                            int p = rt * 16 + ((lane >> 4) << 2) + r;
                            s_red[(wv * 32 + p) * 3 + cur_oc] += v;
                        }
                        acc8[rt][r] = 0.f;
                    }
                cur_oc = oc;
            }
            f32x4 acc[4][2];
            #pragma unroll
            for (int nn = 0; nn < 4; ++nn) { acc[nn][0] = (f32x4){0.f,0.f,0.f,0.f}; acc[nn][1] = acc[nn][0]; }
            for (int kf = 0; kf < 24; ++kf) {
                int koff = kf * 32 + kg;
                f16x8 a0 = *(const f16x8*)(S + pr * 1536 + SWZ(pr, koff * 2));
                int p1 = 16 + pr;
                f16x8 a1 = *(const f16x8*)(S + p1 * 1536 + SWZ(p1, koff * 2));
                f16x8 bq[4];
                #pragma unroll
                for (int nn = 0; nn < 4; ++nn)
                    bq[nn] = *(const f16x8*)(W32T + ((ntb + nn) * 16 + pr) * D2n + koff);
                #pragma unroll
                for (int nn = 0; nn < 4; ++nn) {
                    acc[nn][0] = MFMA16(a0, bq[nn], acc[nn][0]);
                    acc[nn][1] = MFMA16(a1, bq[nn], acc[nn][1]);
                }
            }
            #pragma unroll
            for (int nn = 0; nn < 4; ++nn) {
                int n = (ntb + nn) * 16 + pr;
                float wb = l3b2[n];
                int k  = n & 511;
                int c  = k >> 4, k1 = (k >> 2) & 3, k2 = k & 3;
                const h16* lrr = s_lrr + (c * 4 + k1) * 48;
                #pragma unroll
                for (int rt = 0; rt < 2; ++rt)
                    #pragma unroll
                    for (int r = 0; r < 4; ++r) {
                        int p = rt * 16 + ((lane >> 4) << 2) + r;
                        float sv = (float)lrr[s_sc[p * 4 + k2]];
                        acc8[rt][r] += (acc[nn][rt][r] + wb) * sv;
                    }
            }
        }
        #pragma unroll
        for (int rt = 0; rt < 2; ++rt)
            #pragma unroll
            for (int r = 0; r < 4; ++r) {
                float v = acc8[rt][r];
                v += __shfl_xor(v, 1); v += __shfl_xor(v, 2);
                v += __shfl_xor(v, 4); v += __shfl_xor(v, 8);
                if ((lane & 15) == 0) {
                    int p = rt * 16 + ((lane >> 4) << 2) + r;
                    s_red[(wv * 32 + p) * 3 + cur_oc] += v;
                }
            }
    }
    __syncthreads();

    if (tid < 96) {
        int p = tid / 3, oc = tid % 3;
        float s = s_red[(0 * 32 + p) * 3 + oc] + s_red[(1 * 32 + p) * 3 + oc]
                + s_red[(2 * 32 + p) * 3 + oc] + s_red[(3 * 32 + p) * 3 + oc];
        out[((b * OUTC + oc) * 192 + h) * 192 + (w0 + p)] = tanhf_fast(s);
    }
}

extern "C" void kernel_launch(void* const* d_in, const int* in_sizes, int n_in,
                              void* d_out, int out_size, void* d_ws, size_t ws_size,
                              hipStream_t stream) {
    const float* lr   = (const float*)d_in[0];
    const float* ft_w = (const float*)d_in[4];
    const float* ft_b = (const float*)d_in[5];
    const float* l1w1 = (const float*)d_in[6];
    const float* l1b1 = (const float*)d_in[7];
    const float* l1w2 = (const float*)d_in[8];
    const float* l1b2 = (const float*)d_in[9];
    const float* l2w1 = (const float*)d_in[10];
    const float* l2b1 = (const float*)d_in[11];
    const float* l2w2 = (const float*)d_in[12];
    const float* l2b2 = (const float*)d_in[13];
    const float* l3w1 = (const float*)d_in[14];
    const float* l3b1 = (const float*)d_in[15];
    const float* l3w2 = (const float*)d_in[16];
    const float* l3b2 = (const float*)d_in[17];
    float* outp = (float*)d_out;

    char* ws = (char*)d_ws;
    float* ftmap = (float*)(ws + 0);            // 294912 B
    h16* w12t = (h16*)(ws + 294912);            // 73728 B
    h16* w22t = (h16*)(ws + 368640);            // 73728 B
    h16* w31t = (h16*)(ws + 442368);            // 589824 B
    h16* w32t = (h16*)(ws + 1032192);           // 2359296 B -> ends 3391488
    h16* w11t = (h16*)(ws + 3391488);           // 9216 B
    h16* w21t = (h16*)(ws + 3400704);           // 9216 B  -> ends 3409920
    h16* Gf   = (h16*)(ws + 3409920);           // 113246208 B -> total 116656128

    hipLaunchKernelGGL(prep_kernel, dim3(1514), dim3(256), 0, stream,
                       l1w2, l2w2, l3w1, l3w2, l1w1, l2w1,
                       w12t, w22t, w31t, w32t, w11t, w21t);
    hipLaunchKernelGGL(ft_kernel, dim3(288), dim3(256), 0, stream, lr, ft_w, ft_b, ftmap);

    if (ws_size >= (size_t)116656128) {
        hipLaunchKernelGGL(fused_a, dim3(2304), dim3(256), 0, stream,
                           ftmap, w11t, l1b1, w21t, l2b1,
                           l1b2, l2b2, l3b1,
                           w12t, w22t, w31t, Gf);
        hipLaunchKernelGGL(gemm_b, dim3(1152), dim3(512), 0, stream,
                           lr, Gf, w32t, l3b2, outp);
    } else {
        hipLaunchKernelGGL(fused_fallback, dim3(2304), dim3(256), 0, stream,
                           lr, ftmap,
                           l1w1, l1b1, l2w1, l2b1,
                           l1b2, l2b2, l3b1, l3b2,
                           w12t, w22t, w31t, w32t,
                           outp);
    }
}

// Round 16
// 629.197 us; speedup vs baseline: 4.3212x; 4.3212x over previous
//
#include <hip/hip_runtime.h>
#include <math.h>

#define H_IN   48
#define W_IN   48
#define INC    32
#define OUTC   3
#define FT     16
#define Dn     1536
#define D8n    192
#define D4n    384
#define D2n    768

typedef _Float16 h16;
typedef _Float16 f16x8 __attribute__((ext_vector_type(8)));
typedef _Float16 f16x4 __attribute__((ext_vector_type(4)));
typedef float    f32x4 __attribute__((ext_vector_type(4)));

#define MFMA16(a, b, c) __builtin_amdgcn_mfma_f32_16x16x32_f16((a), (b), (c), 0, 0, 0)

__device__ __forceinline__ int reflect48(int i) {
    return (i < 0) ? -i : ((i > 47) ? 94 - i : i);
}

__device__ __forceinline__ float tanhf_fast(float x) {
    float e = __expf(2.f * x);
    return 1.f - 2.f / (e + 1.f);
}

// row-XOR swizzle: byte column ^ ((row&7)<<4)
#define SWZ(p, bc) ((bc) ^ (((p) & 7) << 4))

// ---------------- feature_trans conv ----------------
__global__ __launch_bounds__(256) void ft_kernel(const float* __restrict__ lr,
                                                 const float* __restrict__ ft_w,
                                                 const float* __restrict__ ft_b,
                                                 float* __restrict__ ftmap) {
    int idx = blockIdx.x * 256 + threadIdx.x;
    if (idx >= 2 * FT * H_IN * W_IN) return;
    int x = idx % W_IN;
    int y = (idx / W_IN) % H_IN;
    int o = (idx / (W_IN * H_IN)) % FT;
    int bb = idx / (W_IN * H_IN * FT);
    float acc = ft_b[o];
    for (int c = 0; c < INC; ++c) {
        const float* lrc = lr + ((bb * INC + c) * H_IN) * W_IN;
        const float* wc  = ft_w + ((o * INC + c) * 4) * 4;
        #pragma unroll
        for (int dy = 0; dy < 4; ++dy) {
            int ry = reflect48(y + dy - 1);
            #pragma unroll
            for (int dx = 0; dx < 4; ++dx) {
                int rx = reflect48(x + dx - 1);
                acc += lrc[ry * W_IN + rx] * wc[dy * 4 + dx];
            }
        }
    }
    ftmap[idx] = acc;
}

// ---------------- weight transpose + f32->f16 ----------------
// bids 0..1511: big-weight transposes. bids 1512/1513: l{1,2}w1 -> [192][24] f16
__global__ __launch_bounds__(256) void prep_kernel(const float* __restrict__ l1w2,
                                                   const float* __restrict__ l2w2,
                                                   const float* __restrict__ l3w1,
                                                   const float* __restrict__ l3w2,
                                                   const float* __restrict__ l1w1,
                                                   const float* __restrict__ l2w1,
                                                   h16* __restrict__ w12t, h16* __restrict__ w22t,
                                                   h16* __restrict__ w31t, h16* __restrict__ w32t,
                                                   h16* __restrict__ w11t, h16* __restrict__ w21t) {
    __shared__ float tile[32][33];
    int bid = blockIdx.x;
    if (bid >= 1512) {
        const float* s = (bid == 1512) ? l1w1 : l2w1;
        h16* d = (bid == 1512) ? w11t : w21t;
        int j = threadIdx.x;
        if (j < 192) {
            #pragma unroll
            for (int i = 0; i < 20; ++i) d[j * 24 + i] = (h16)s[i * 192 + j];
            #pragma unroll
            for (int i = 20; i < 24; ++i) d[j * 24 + i] = (h16)0.f;
        }
        return;
    }
    const float* src; h16* dst; int K, N, t0;
    if (bid < 36)      { src = l1w2; dst = w12t; K = 192; N = 192;  t0 = 0; }
    else if (bid < 72) { src = l2w2; dst = w22t; K = 192; N = 192;  t0 = 36; }
    else if (bid < 360){ src = l3w1; dst = w31t; K = 384; N = 768;  t0 = 72; }
    else               { src = l3w2; dst = w32t; K = 768; N = 1536; t0 = 360; }
    int t = bid - t0;
    int ntx = N >> 5;
    int kt = t / ntx, nt = t - kt * ntx;
    int k0 = kt << 5, n0 = nt << 5;
    int tx = threadIdx.x & 31, ty = threadIdx.x >> 5;
    #pragma unroll
    for (int i = 0; i < 4; ++i)
        tile[ty + i * 8][tx] = src[(k0 + ty + i * 8) * N + n0 + tx];
    __syncthreads();
    #pragma unroll
    for (int i = 0; i < 4; ++i)
        dst[(n0 + ty + i * 8) * K + k0 + tx] = (h16)tile[tx][ty + i * 8];
}

// =================================================================
// Kernel A: phases 0-4 (MLP up to g), 32 pixels/block, writes g-frags
// Gf export uses NON-TEMPORAL stores (read-once data; keeps W panels
// L2-resident).
// =================================================================
#define A_OFF_H1   0
#define A_OFF_H2   12288
#define A_OFF_OSF  24576
#define A_OFF_F    0
#define A_OFF_G    0
#define A_S_BYTES  49152

__global__ __launch_bounds__(256, 3) void fused_a(
    const float* __restrict__ ftmap,
    const h16* __restrict__ W11T, const float* __restrict__ l1b1,
    const h16* __restrict__ W21T, const float* __restrict__ l2b1,
    const float* __restrict__ l1b2, const float* __restrict__ l2b2,
    const float* __restrict__ l3b1,
    const h16* __restrict__ W12T, const h16* __restrict__ W22T,
    const h16* __restrict__ W31T,
    h16* __restrict__ Gf)
{
    __shared__ __align__(16) char S[A_S_BYTES];

    const int tid  = threadIdx.x;
    const int lane = tid & 63;
    const int wv   = tid >> 6;
    const int bid  = blockIdx.x;
    const int b    = bid / 1152;
    const int rem  = bid % 1152;
    const int h    = rem / 6;
    const int w0   = (rem % 6) * 32;

    const float ch = (h + 1) * 0.25f - 0.625f;
    const int   fh = (int)floorf(ch);
    const float offh = (float)fh - ch;
    const int   rfh = reflect48(fh);

    float* s_osf = (float*)(S + A_OFF_OSF);

    // ---------- phase 0: osf ----------
    if (tid < 32) {
        int w = w0 + tid;
        float cw = (w + 1) * 0.25f - 0.625f;
        int fw = (int)floorf(cw);
        float* o = s_osf + tid * 20;
        o[16] = offh; o[17] = (float)fw - cw; o[18] = 4.f; o[19] = 4.f;
    }
    {   // srf gather: 32p x 16ch
        int p = tid >> 3;
        int c0 = (tid & 7) * 2;
        int w = w0 + p;
        float cw = (w + 1) * 0.25f - 0.625f;
        int rfw = reflect48((int)floorf(cw));
        float* o = s_osf + p * 20;
        o[c0]     = ftmap[((b * FT + c0) * H_IN + rfh) * W_IN + rfw];
        o[c0 + 1] = ftmap[((b * FT + c0 + 1) * H_IN + rfh) * W_IN + rfw];
    }
    __syncthreads();

    // ---------- phase 1: h{1,2} = tanh(osf @ W1 + b), W1 rows f16 contiguous ----------
    for (int idx = tid; idx < 2 * 32 * D8n; idx += 256) {
        int br = idx / 6144;
        int r2 = idx - br * 6144;
        int p  = r2 / D8n;
        int j  = r2 - p * D8n;
        const h16* Wt = (br ? W21T : W11T) + j * 24;
        const float* B = br ? l2b1 : l1b1;
        const float* o = s_osf + p * 20;
        float acc = B[j];
        f16x8 wa = *(const f16x8*)(Wt);
        f16x8 wb = *(const f16x8*)(Wt + 8);
        f16x4 wc = *(const f16x4*)(Wt + 16);
        #pragma unroll
        for (int i = 0; i < 8; ++i) acc += o[i] * (float)wa[i];
        #pragma unroll
        for (int i = 0; i < 8; ++i) acc += o[8 + i] * (float)wb[i];
        #pragma unroll
        for (int i = 0; i < 4; ++i) acc += o[16 + i] * (float)wc[i];
        int base = br ? A_OFF_H2 : A_OFF_H1;
        *(h16*)(S + base + p * 384 + SWZ(p, j * 2)) = (h16)tanhf_fast(acc);
    }
    __syncthreads();

    // ---------- phase 2 A-load ----------
    f16x8 Ah[2][2][6];
    {
        int pr = lane & 15, kg = (lane >> 4) << 3;
        #pragma unroll
        for (int br = 0; br < 2; ++br)
            #pragma unroll
            for (int rt = 0; rt < 2; ++rt) {
                int p = rt * 16 + pr;
                #pragma unroll
                for (int kf = 0; kf < 6; ++kf) {
                    int k0 = kf * 32 + kg;
                    Ah[br][rt][kf] = *(const f16x8*)(S + (br ? A_OFF_H2 : A_OFF_H1) + p * 384 + SWZ(p, k0 * 2));
                }
            }
    }
    __syncthreads();

    // ---------- phase 2 compute + merge -> f ----------
    {
        int pr = lane & 15, kg = (lane >> 4) << 3;
        #pragma unroll
        for (int cc = 0; cc < 3; ++cc) {
            int c = wv * 3 + cc;
            int n = c * 16 + pr;
            f32x4 a00 = {0.f,0.f,0.f,0.f}, a01 = a00, a10 = a00, a11 = a00;
            #pragma unroll
            for (int kf = 0; kf < 6; ++kf) {
                int koff = kf * 32 + kg;
                f16x8 b0 = *(const f16x8*)(W12T + n * D8n + koff);
                f16x8 b1 = *(const f16x8*)(W22T + n * D8n + koff);
                a00 = MFMA16(Ah[0][0][kf], b0, a00);
                a01 = MFMA16(Ah[0][1][kf], b0, a01);
                a10 = MFMA16(Ah[1][0][kf], b1, a10);
                a11 = MFMA16(Ah[1][1][kf], b1, a11);
            }
            float bf1 = l1b2[n], bf2 = l2b2[n];
            #pragma unroll
            for (int rt = 0; rt < 2; ++rt) {
                #pragma unroll
                for (int r = 0; r < 4; ++r) {
                    int p = rt * 16 + ((lane >> 4) << 2) + r;
                    float f1 = (rt ? a01[r] : a00[r]) + bf1;
                    float f2 = (rt ? a11[r] : a10[r]) + bf2;
                    *(h16*)(S + A_OFF_F + p * 768 + SWZ(p, n * 2))         = (h16)tanhf_fast(f1 * f2);
                    *(h16*)(S + A_OFF_F + p * 768 + SWZ(p, (n + D8n) * 2)) = (h16)tanhf_fast(f1);
                }
            }
        }
    }
    __syncthreads();

    // ---------- phase 4 A-load ----------
    f16x8 Af[2][12];
    {
        int pr = lane & 15, kg = (lane >> 4) << 3;
        #pragma unroll
        for (int rt = 0; rt < 2; ++rt) {
            int p = rt * 16 + pr;
            #pragma unroll
            for (int kf = 0; kf < 12; ++kf) {
                int k0 = kf * 32 + kg;
                Af[rt][kf] = *(const f16x8*)(S + A_OFF_F + p * 768 + SWZ(p, k0 * 2));
            }
        }
    }
    __syncthreads();

    // ---------- phase 4 compute: g = leaky(f @ l3w1 + b) -> g LDS ----------
    {
        int pr = lane & 15, kg = (lane >> 4) << 3;
        #pragma unroll
        for (int q = 0; q < 3; ++q) {
            int ntb = wv * 12 + q * 4;
            f32x4 acc[4][2];
            #pragma unroll
            for (int nn = 0; nn < 4; ++nn) { acc[nn][0] = (f32x4){0.f,0.f,0.f,0.f}; acc[nn][1] = acc[nn][0]; }
            for (int kf = 0; kf < 12; ++kf) {
                int koff = kf * 32 + kg;
                f16x8 bq[4];
                #pragma unroll
                for (int nn = 0; nn < 4; ++nn)
                    bq[nn] = *(const f16x8*)(W31T + ((ntb + nn) * 16 + pr) * D4n + koff);
                #pragma unroll
                for (int nn = 0; nn < 4; ++nn) {
                    acc[nn][0] = MFMA16(Af[0][kf], bq[nn], acc[nn][0]);
                    acc[nn][1] = MFMA16(Af[1][kf], bq[nn], acc[nn][1]);
                }
            }
            #pragma unroll
            for (int nn = 0; nn < 4; ++nn) {
                int n = (ntb + nn) * 16 + pr;
                float bb = l3b1[n];
                #pragma unroll
                for (int rt = 0; rt < 2; ++rt) {
                    #pragma unroll
                    for (int r = 0; r < 4; ++r) {
                        int p = rt * 16 + ((lane >> 4) << 2) + r;
                        float gv = acc[nn][rt][r] + bb;
                        gv = (gv > 0.f) ? gv : 0.01f * gv;
                        *(h16*)(S + A_OFF_G + p * 1536 + SWZ(p, n * 2)) = (h16)gv;
                    }
                }
            }
        }
    }
    __syncthreads();

    // ---------- phase 5': export g as MFMA B-fragments, non-temporal ----------
    {
        int pr = lane & 15, kg = lane >> 4;
        int ptg0 = (b * 192 + h) * 12 + (w0 >> 4);
        #pragma unroll
        for (int i = 0; i < 12; ++i) {
            int pair = wv * 12 + i;           // 0..47
            int rt = pair / 24, kf = pair % 24;
            int p = rt * 16 + pr;
            f16x8 v = *(const f16x8*)(S + A_OFF_G + p * 1536 + SWZ(p, (kf * 32 + kg * 8) * 2));
            size_t e = ((size_t)((ptg0 + rt) * 24 + kf) * 4 + kg) * 16 + pr;
            __builtin_nontemporal_store(v, (f16x8*)(Gf + e * 8));
        }
    }
}

// =================================================================
// Kernel B (r12-exact, best stable: 385 us): K-split across waves +
// scalar row-cache epilogue + rotating W triples + non-temporal Gf
// reads. Compiler owns all scheduling (every pinning attempt was
// neutral-or-worse: r7, r13, r14).
// =================================================================
__global__ __launch_bounds__(512, 4) void gemm_b(
    const float* __restrict__ lr,
    const h16* __restrict__ Gf,
    const h16* __restrict__ W32T,
    const float* __restrict__ l3b2,
    float* __restrict__ out)
{
    __shared__ float s_lr[32][4][20];         // 10240 B
    __shared__ float s_red[8][64][3];         // 6144 B

    const int tid  = threadIdx.x;
    const int lane = tid & 63;
    const int wvv  = tid >> 6;                // 0..7
    const int pr   = lane & 15;
    const int kg   = lane >> 4;               // 0..3

    const int bid = blockIdx.x;
    const int b   = bid / 576;
    const int rem = bid % 576;
    const int h   = rem / 3;
    const int w0  = (rem % 3) * 64;
    const int w4  = w0 >> 2;

    const float chh = (h + 1) * 0.25f - 0.625f;
    const int fh = (int)floorf(chh);

    // ---------- stage reflect-padded lr row cache ----------
    for (int idx = tid; idx < 32 * 4 * 20; idx += 512) {
        int c  = idx / 80;
        int r2 = idx - c * 80;
        int k1 = r2 / 20;
        int j  = r2 - k1 * 20;
        int row = reflect48(fh - 1 + k1);
        int col = reflect48(w4 - 2 + j);
        s_lr[c][k1][j] = lr[((b * INC + c) * H_IN + row) * W_IN + col];
    }
    __syncthreads();

    // ---------- bias-dot: s_red[part][p][oc] = sum_{k in part-slice} b[oc*512+k]*sel[p,k]
    {
        int p = tid >> 3, part = tid & 7;
        int jbp = (int)floorf((w0 + p + 1) * 0.25f - 0.625f) - w4 + 1;
        float s0 = 0.f, s1 = 0.f, s2 = 0.f;
        #pragma unroll
        for (int j = 0; j < 16; ++j) {
            int k  = part * 4 + j * 32;
            int c  = k >> 4;
            int k1 = (k >> 2) & 3;
            const float* lrow = &s_lr[c][k1][jbp];
            float4 ba  = *(const float4*)(l3b2 + k);
            float4 bbv = *(const float4*)(l3b2 + 512 + k);
            float4 bc  = *(const float4*)(l3b2 + 1024 + k);
            #pragma unroll
            for (int r = 0; r < 4; ++r) {
                float sv = lrow[r];
                s0 += ((const float*)&ba)[r]  * sv;
                s1 += ((const float*)&bbv)[r] * sv;
                s2 += ((const float*)&bc)[r]  * sv;
            }
        }
        s_red[part][p][0] = s0; s_red[part][p][1] = s1; s_red[part][p][2] = s2;
    }
    __syncthreads();

    const int ptB = (b * 192 + h) * 12 + (w0 >> 4);

    // per-lane column offsets into s_lr rows, one per pixel-tile
    const int jb0 = (int)floorf((w0 + pr      + 1) * 0.25f - 0.625f) - w4 + 1;
    const int jb1 = (int)floorf((w0 + pr + 16 + 1) * 0.25f - 0.625f) - w4 + 1;
    const int jb2 = (int)floorf((w0 + pr + 32 + 1) * 0.25f - 0.625f) - w4 + 1;
    const int jb3 = (int)floorf((w0 + pr + 48 + 1) * 0.25f - 0.625f) - w4 + 1;

    // ---------- gB frags for this wave's K-slice (kf = wvv*3 + {0,1,2}), nt loads ----------
    f16x8 gB[4][3];
    {
        const h16* Gbase = Gf + (size_t)(kg * 16 + pr) * 8;
        #pragma unroll
        for (int pt = 0; pt < 4; ++pt)
            #pragma unroll
            for (int kfl = 0; kfl < 3; ++kfl)
                gB[pt][kfl] = __builtin_nontemporal_load((const f16x8*)(Gbase +
                    ((size_t)((ptB + pt) * 24 + (wvv * 3 + kfl)) * 64) * 8));
    }

    const h16* Wbase = W32T + (size_t)pr * D2n + wvv * 96 + kg * 8;

    float acc0[4], acc1[4], acc2[4];
    #pragma unroll
    for (int pt = 0; pt < 4; ++pt) { acc0[pt] = 0.f; acc1[pt] = 0.f; acc2[pt] = 0.f; }

    const f32x4 z4 = {0.f, 0.f, 0.f, 0.f};

    f16x8 A0, A1, A2, B0, B1, B2, C0, C1, C2;

    #define LOADW(NT, T0_, T1_, T2_) {                                             \
        int n_ = (NT); n_ = (n_ > 95) ? 95 : n_;                                   \
        const h16* p_ = Wbase + (size_t)n_ * (16 * D2n);                           \
        T0_ = *(const f16x8*)(p_);                                                 \
        T1_ = *(const f16x8*)(p_ + 32);                                            \
        T2_ = *(const f16x8*)(p_ + 64);                                            \
    }

    // step NT: issue load for NT+2 into (N*), 12 MFMA on (W*), row-cache epilogue
    #define STEP(NT, W0_, W1_, W2_, N0_, N1_, N2_) {                               \
        LOADW((NT) + 2, N0_, N1_, N2_)                                             \
        f32x4 w0_ = MFMA16(W0_, gB[0][0], z4);                                     \
        f32x4 w1_ = MFMA16(W0_, gB[1][0], z4);                                     \
        f32x4 w2_ = MFMA16(W0_, gB[2][0], z4);                                     \
        f32x4 w3_ = MFMA16(W0_, gB[3][0], z4);                                     \
        w0_ = MFMA16(W1_, gB[0][1], w0_);                                          \
        w1_ = MFMA16(W1_, gB[1][1], w1_);                                          \
        w2_ = MFMA16(W1_, gB[2][1], w2_);                                          \
        w3_ = MFMA16(W1_, gB[3][1], w3_);                                          \
        w0_ = MFMA16(W2_, gB[0][2], w0_);                                          \
        w1_ = MFMA16(W2_, gB[1][2], w1_);                                          \
        w2_ = MFMA16(W2_, gB[2][2], w2_);                                          \
        w3_ = MFMA16(W2_, gB[3][2], w3_);                                          \
        const int nt_ = (NT);                                                      \
        const float* lrow_ = &s_lr[nt_ & 31][kg][0];                               \
        float e0_ = w0_[0] * lrow_[jb0]     + w0_[1] * lrow_[jb0 + 1]              \
                  + w0_[2] * lrow_[jb0 + 2] + w0_[3] * lrow_[jb0 + 3];             \
        float e1_ = w1_[0] * lrow_[jb1]     + w1_[1] * lrow_[jb1 + 1]              \
                  + w1_[2] * lrow_[jb1 + 2] + w1_[3] * lrow_[jb1 + 3];             \
        float e2_ = w2_[0] * lrow_[jb2]     + w2_[1] * lrow_[jb2 + 1]              \
                  + w2_[2] * lrow_[jb2 + 2] + w2_[3] * lrow_[jb2 + 3];             \
        float e3_ = w3_[0] * lrow_[jb3]     + w3_[1] * lrow_[jb3 + 1]              \
                  + w3_[2] * lrow_[jb3 + 2] + w3_[3] * lrow_[jb3 + 3];             \
        const int oc_ = nt_ >> 5;                                                  \
        if (oc_ == 0)      { acc0[0] += e0_; acc0[1] += e1_; acc0[2] += e2_; acc0[3] += e3_; } \
        else if (oc_ == 1) { acc1[0] += e0_; acc1[1] += e1_; acc1[2] += e2_; acc1[3] += e3_; } \
        else               { acc2[0] += e0_; acc2[1] += e1_; acc2[2] += e2_; acc2[3] += e3_; } \
    }

    LOADW(0, A0, A1, A2)
    LOADW(1, B0, B1, B2)
    for (int g = 0; g < 32; ++g) {
        const int t0 = 3 * g;
        STEP(t0,     A0, A1, A2, C0, C1, C2)
        STEP(t0 + 1, B0, B1, B2, A0, A1, A2)
        STEP(t0 + 2, C0, C1, C2, B0, B1, B2)
    }
    #undef LOADW
    #undef STEP

    // ---------- cross-lane (kg) reduce, then += into this wave's s_red slot ----------
    #pragma unroll
    for (int pt = 0; pt < 4; ++pt) {
        float v0 = acc0[pt], v1 = acc1[pt], v2 = acc2[pt];
        v0 += __shfl_xor(v0, 16); v0 += __shfl_xor(v0, 32);
        v1 += __shfl_xor(v1, 16); v1 += __shfl_xor(v1, 32);
        v2 += __shfl_xor(v2, 16); v2 += __shfl_xor(v2, 32);
        if (lane < 16) {
            float* r = &s_red[wvv][pt * 16 + pr][0];
            r[0] += v0; r[1] += v1; r[2] += v2;
        }
    }
    __syncthreads();
    if (tid < 192) {
        int p = tid / 3, oc = tid % 3;
        float s = 0.f;
        #pragma unroll
        for (int wv2 = 0; wv2 < 8; ++wv2) s += s_red[wv2][p][oc];
        out[((b * OUTC + oc) * 192 + h) * 192 + (w0 + p)] = tanhf_fast(s);
    }
}

// =================================================================
// Fallback (round-2 single fused kernel) if ws too small
// =================================================================
__global__ __launch_bounds__(256, 2) void fused_fallback(
    const float* __restrict__ lr, const float* __restrict__ ftmap,
    const float* __restrict__ l1w1, const float* __restrict__ l1b1,
    const float* __restrict__ l2w1, const float* __restrict__ l2b1,
    const float* __restrict__ l1b2, const float* __restrict__ l2b2,
    const float* __restrict__ l3b1, const float* __restrict__ l3b2,
    const h16* __restrict__ W12T, const h16* __restrict__ W22T,
    const h16* __restrict__ W31T, const h16* __restrict__ W32T,
    float* __restrict__ out)
{
    __shared__ __align__(16) char S[63104];
    const int tid  = threadIdx.x;
    const int lane = tid & 63;
    const int wv   = tid >> 6;
    const int bid  = blockIdx.x;
    const int b    = bid / 1152;
    const int rem  = bid % 1152;
    const int h    = rem / 6;
    const int w0   = (rem % 6) * 32;

    const float ch = (h + 1) * 0.25f - 0.625f;
    const int   fh = (int)floorf(ch);
    const float offh = (float)fh - ch;
    const int   rfh = reflect48(fh);

    float* s_osf = (float*)(S + 24576);
    unsigned char* s_sc = (unsigned char*)(S + 61440);
    h16*   s_lrr = (h16*)(S + 49152);
    float* s_red = (float*)(S + 61568);

    if (tid < 128) {
        int p = tid >> 2, k2 = tid & 3;
        int w = w0 + p;
        float cw = (w + 1) * 0.25f - 0.625f;
        int fw = (int)floorf(cw);
        s_sc[p * 4 + k2] = (unsigned char)reflect48(fw - 1 + k2);
        if (k2 == 0) {
            float* o = s_osf + p * 20;
            o[16] = offh; o[17] = (float)fw - cw; o[18] = 4.f; o[19] = 4.f;
        }
    }
    {
        int p = tid >> 3;
        int c0 = (tid & 7) * 2;
        int w = w0 + p;
        float cw = (w + 1) * 0.25f - 0.625f;
        int rfw = reflect48((int)floorf(cw));
        float* o = s_osf + p * 20;
        o[c0]     = ftmap[((b * FT + c0) * H_IN + rfh) * W_IN + rfw];
        o[c0 + 1] = ftmap[((b * FT + c0 + 1) * H_IN + rfh) * W_IN + rfw];
    }
    for (int idx = tid; idx < 32 * 4 * 48; idx += 256) {
        int c = idx / 192, r2 = idx - c * 192, k1 = r2 / 48, col = r2 - k1 * 48;
        int row = reflect48(fh - 1 + k1);
        s_lrr[idx] = (h16)lr[((b * INC + c) * H_IN + row) * W_IN + col];
    }
    for (int idx = tid; idx < 4 * 32 * 3; idx += 256) s_red[idx] = 0.f;
    __syncthreads();

    for (int idx = tid; idx < 2 * 32 * D8n; idx += 256) {
        int br = idx / 6144;
        int r2 = idx - br * 6144;
        int p  = r2 / D8n;
        int j  = r2 - p * D8n;
        const float* W = br ? l2w1 : l1w1;
        const float* B = br ? l2b1 : l1b1;
        const float* o = s_osf + p * 20;
        float acc = B[j];
        #pragma unroll
        for (int i = 0; i < 20; ++i) acc += o[i] * W[i * D8n + j];
        int base = br ? 12288 : 0;
        *(h16*)(S + base + p * 384 + SWZ(p, j * 2)) = (h16)tanhf_fast(acc);
    }
    __syncthreads();

    f16x8 Ah[2][2][6];
    {
        int pr = lane & 15, kg = (lane >> 4) << 3;
        #pragma unroll
        for (int br = 0; br < 2; ++br)
            #pragma unroll
            for (int rt = 0; rt < 2; ++rt) {
                int p = rt * 16 + pr;
                #pragma unroll
                for (int kf = 0; kf < 6; ++kf)
                    Ah[br][rt][kf] = *(const f16x8*)(S + (br ? 12288 : 0) + p * 384 + SWZ(p, (kf * 32 + kg) * 2));
            }
    }
    __syncthreads();

    {
        int pr = lane & 15, kg = (lane >> 4) << 3;
        #pragma unroll
        for (int cc = 0; cc < 3; ++cc) {
            int c = wv * 3 + cc;
            int n = c * 16 + pr;
            f32x4 a00 = {0.f,0.f,0.f,0.f}, a01 = a00, a10 = a00, a11 = a00;
            #pragma unroll
            for (int kf = 0; kf < 6; ++kf) {
                int koff = kf * 32 + kg;
                f16x8 b0 = *(const f16x8*)(W12T + n * D8n + koff);
                f16x8 b1 = *(const f16x8*)(W22T + n * D8n + koff);
                a00 = MFMA16(Ah[0][0][kf], b0, a00);
                a01 = MFMA16(Ah[0][1][kf], b0, a01);
                a10 = MFMA16(Ah[1][0][kf], b1, a10);
                a11 = MFMA16(Ah[1][1][kf], b1, a11);
            }
            float bf1 = l1b2[n], bf2 = l2b2[n];
            #pragma unroll
            for (int rt = 0; rt < 2; ++rt)
                #pragma unroll
                for (int r = 0; r < 4; ++r) {
                    int p = rt * 16 + ((lane >> 4) << 2) + r;
                    float f1 = (rt ? a01[r] : a00[r]) + bf1;
                    float f2 = (rt ? a11[r] : a10[r]) + bf2;
                    *(h16*)(S + p * 768 + SWZ(p, n * 2))         = (h16)tanhf_fast(f1 * f2);
                    *(h16*)(S + p * 768 + SWZ(p, (n + D8n) * 2)) = (h16)tanhf_fast(f1);
                }
        }
    }
    __syncthreads();

    f16x8 Af[2][12];
    {
        int pr = lane & 15, kg = (lane >> 4) << 3;
        #pragma unroll
        for (int rt = 0; rt < 2; ++rt) {
            int p = rt * 16 + pr;
            #pragma unroll
            for (int kf = 0; kf < 12; ++kf)
                Af[rt][kf] = *(const f16x8*)(S + p * 768 + SWZ(p, (kf * 32 + kg) * 2));
        }
    }
    __syncthreads();

    {
        int pr = lane & 15, kg = (lane >> 4) << 3;
        #pragma unroll
        for (int q = 0; q < 3; ++q) {
            int ntb = wv * 12 + q * 4;
            f32x4 acc[4][2];
            #pragma unroll
            for (int nn = 0; nn < 4; ++nn) { acc[nn][0] = (f32x4){0.f,0.f,0.f,0.f}; acc[nn][1] = acc[nn][0]; }
            for (int kf = 0; kf < 12; ++kf) {
                int koff = kf * 32 + kg;
                f16x8 bq[4];
                #pragma unroll
                for (int nn = 0; nn < 4; ++nn)
                    bq[nn] = *(const f16x8*)(W31T + ((ntb + nn) * 16 + pr) * D4n + koff);
                #pragma unroll
                for (int nn = 0; nn < 4; ++nn) {
                    acc[nn][0] = MFMA16(Af[0][kf], bq[nn], acc[nn][0]);
                    acc[nn][1] = MFMA16(Af[1][kf], bq[nn], acc[nn][1]);
                }
            }
            #pragma unroll
            for (int nn = 0; nn < 4; ++nn) {
                int n = (ntb + nn) * 16 + pr;
                float bb = l3b1[n];
                #pragma unroll
                for (int rt = 0; rt < 2; ++rt)
                    #pragma unroll
                    for (int r = 0; r < 4; ++r) {
                        int p = rt * 16 + ((lane >> 4) << 2) + r;
                        float gv = acc[nn][rt][r] + bb;
                        gv = (gv > 0.f) ? gv : 0.01f * gv;
                        *(h16*)(S + p * 1536 + SWZ(p, n * 2)) = (h16)gv;
                    }
            }
        }
    }
    __syncthreads();

    {
        int pr = lane & 15, kg = (lane >> 4) << 3;
        float acc8[2][4];
        #pragma unroll
        for (int rt = 0; rt < 2; ++rt)
            #pragma unroll
            for (int r = 0; r < 4; ++r) acc8[rt][r] = 0.f;
        int cur_oc = (wv * 24) >> 5;

        for (int q = 0; q < 6; ++q) {
            int ntb = wv * 24 + q * 4;
            int oc = ntb >> 5;
            if (oc != cur_oc) {
                #pragma unroll
                for (int rt = 0; rt < 2; ++rt)
                    #pragma unroll
                    for (int r = 0; r < 4; ++r) {
                        float v = acc8[rt][r];
                        v += __shfl_xor(v, 1); v += __shfl_xor(v, 2);
                        v += __shfl_xor(v, 4); v += __shfl_xor(v, 8);
                        if ((lane & 15) == 0) {
                            int p = rt * 16 + ((lane >> 4) << 2) + r;
                            s_red[(wv * 32 + p) * 3 + cur_oc] += v;
                        }
                        acc8[rt][r] = 0.f;
                    }
                cur_oc = oc;
            }
            f32x4 acc[4][2];
            #pragma unroll
            for (int nn = 0; nn < 4; ++nn) { acc[nn][0] = (f32x4){0.f,0.f,0.f,0.f}; acc[nn][1] = acc[nn][0]; }
            for (int kf = 0; kf < 24; ++kf) {
                int koff = kf * 32 + kg;
                f16x8 a0 = *(const f16x8*)(S + pr * 1536 + SWZ(pr, koff * 2));
                int p1 = 16 + pr;
                f16x8 a1 = *(const f16x8*)(S + p1 * 1536 + SWZ(p1, koff * 2));
                f16x8 bq[4];
                #pragma unroll
                for (int nn = 0; nn < 4; ++nn)
                    bq[nn] = *(const f16x8*)(W32T + ((ntb + nn) * 16 + pr) * D2n + koff);
                #pragma unroll
                for (int nn = 0; nn < 4; ++nn) {
                    acc[nn][0] = MFMA16(a0, bq[nn], acc[nn][0]);
                    acc[nn][1] = MFMA16(a1, bq[nn], acc[nn][1]);
                }
            }
            #pragma unroll
            for (int nn = 0; nn < 4; ++nn) {
                int n = (ntb + nn) * 16 + pr;
                float wb = l3b2[n];
                int k  = n & 511;
                int c  = k >> 4, k1 = (k >> 2) & 3, k2 = k & 3;
                const h16* lrr = s_lrr + (c * 4 + k1) * 48;
                #pragma unroll
                for (int rt = 0; rt < 2; ++rt)
                    #pragma unroll
                    for (int r = 0; r < 4; ++r) {
                        int p = rt * 16 + ((lane >> 4) << 2) + r;
                        float sv = (float)lrr[s_sc[p * 4 + k2]];
                        acc8[rt][r] += (acc[nn][rt][r] + wb) * sv;
                    }
            }
        }
        #pragma unroll
        for (int rt = 0; rt < 2; ++rt)
            #pragma unroll
            for (int r = 0; r < 4; ++r) {
                float v = acc8[rt][r];
                v += __shfl_xor(v, 1); v += __shfl_xor(v, 2);
                v += __shfl_xor(v, 4); v += __shfl_xor(v, 8);
                if ((lane & 15) == 0) {
                    int p = rt * 16 + ((lane >> 4) << 2) + r;
                    s_red[(wv * 32 + p) * 3 + cur_oc] += v;
                }
            }
    }
    __syncthreads();

    if (tid < 96) {
        int p = tid / 3, oc = tid % 3;
        float s = s_red[(0 * 32 + p) * 3 + oc] + s_red[(1 * 32 + p) * 3 + oc]
                + s_red[(2 * 32 + p) * 3 + oc] + s_red[(3 * 32 + p) * 3 + oc];
        out[((b * OUTC + oc) * 192 + h) * 192 + (w0 + p)] = tanhf_fast(s);
    }
}

extern "C" void kernel_launch(void* const* d_in, const int* in_sizes, int n_in,
                              void* d_out, int out_size, void* d_ws, size_t ws_size,
                              hipStream_t stream) {
    const float* lr   = (const float*)d_in[0];
    const float* ft_w = (const float*)d_in[4];
    const float* ft_b = (const float*)d_in[5];
    const float* l1w1 = (const float*)d_in[6];
    const float* l1b1 = (const float*)d_in[7];
    const float* l1w2 = (const float*)d_in[8];
    const float* l1b2 = (const float*)d_in[9];
    const float* l2w1 = (const float*)d_in[10];
    const float* l2b1 = (const float*)d_in[11];
    const float* l2w2 = (const float*)d_in[12];
    const float* l2b2 = (const float*)d_in[13];
    const float* l3w1 = (const float*)d_in[14];
    const float* l3b1 = (const float*)d_in[15];
    const float* l3w2 = (const float*)d_in[16];
    const float* l3b2 = (const float*)d_in[17];
    float* outp = (float*)d_out;

    char* ws = (char*)d_ws;
    float* ftmap = (float*)(ws + 0);            // 294912 B
    h16* w12t = (h16*)(ws + 294912);            // 73728 B
    h16* w22t = (h16*)(ws + 368640);            // 73728 B
    h16* w31t = (h16*)(ws + 442368);            // 589824 B
    h16* w32t = (h16*)(ws + 1032192);           // 2359296 B -> ends 3391488
    h16* w11t = (h16*)(ws + 3391488);           // 9216 B
    h16* w21t = (h16*)(ws + 3400704);           // 9216 B  -> ends 3409920
    h16* Gf   = (h16*)(ws + 3409920);           // 113246208 B -> total 116656128

    hipLaunchKernelGGL(prep_kernel, dim3(1514), dim3(256), 0, stream,
                       l1w2, l2w2, l3w1, l3w2, l1w1, l2w1,
                       w12t, w22t, w31t, w32t, w11t, w21t);
    hipLaunchKernelGGL(ft_kernel, dim3(288), dim3(256), 0, stream, lr, ft_w, ft_b, ftmap);

    if (ws_size >= (size_t)116656128) {
        hipLaunchKernelGGL(fused_a, dim3(2304), dim3(256), 0, stream,
                           ftmap, w11t, l1b1, w21t, l2b1,
                           l1b2, l2b2, l3b1,
                           w12t, w22t, w31t, Gf);
        hipLaunchKernelGGL(gemm_b, dim3(1152), dim3(512), 0, stream,
                           lr, Gf, w32t, l3b2, outp);
    } else {
        hipLaunchKernelGGL(fused_fallback, dim3(2304), dim3(256), 0, stream,
                           lr, ftmap,
                           l1w1, l1b1, l2w1, l2b1,
                           l1b2, l2b2, l3b1, l3b2,
                           w12t, w22t, w31t, w32t,
                           outp);
    }
}